// Round 1
// baseline (87.868 us; speedup 1.0000x reference)
//
#include <hip/hip_runtime.h>

// BPNet fused forward: E=16384, ORDER=3, D=13, RANK=128, NUM_PARAMS=4.
// R11: factor stage 1 out of the per-edge kernel.
//   t(e,o) = relu(nodes[edges[e,o]] @ W1[et[e,o]] + b1) depends only on
//   (node, type): 16K distinct pairs vs 49K per-slot evaluations (3x
//   redundancy). bpnet_prep computes T[node][ty][128] f32 once with the
//   bit-identical f16-dot2 pipeline; bpnet_edge gathers T rows coalesced
//   (float4, 512B/group) and runs stage 2 only. Per-edge LDS traffic
//   halves (21KB -> 10KB), LDS footprint 60KB -> 40.7KB, per-lane VALU
//   halves. NUM_ITERS loop in reference is idempotent -> one iteration.

#define DD 13
#define OD 3
#define NP 4
#define RK 128

typedef unsigned int uint;
typedef _Float16 h2 __attribute__((ext_vector_type(2)));

// ---- ws dword layout ----
#define W2H_OFF 0                    // [12][13][64] h2: dword c -> ranks (2c,2c+1), dim dd
#define W2H_N   (12 * 13 * 64)       // 9984
#define HOB_OFF (W2H_OFF + W2H_N)    // [12][16] f32 (dd>=13 zeroed)
#define HOB_N   (12 * 16)            // 192
#define TAB_N   (HOB_OFF + HOB_N)    // 10176 dwords = 40704 B
#define T_OFF   10240                // [N][4][128] f32 = 8 MB

// ---- prep-kernel LDS layout (dwords) ----
#define L_W1A 0                      // [4][7][64] h2: c=4g+k -> rank 8g+k, d-pair p
#define L_W1B 1792                   // [4][7][64]: rank 8g+4+k
#define L_B1A 3584                   // [4][64] f32: rank 8g+k
#define L_B1B 3840                   // [4][64] f32: rank 8g+4+k
#define L_N   4096

__device__ __forceinline__ uint pk(float lo, float hi) {
    return __builtin_bit_cast(uint, __builtin_amdgcn_cvt_pkrtz(lo, hi));
}
__device__ __forceinline__ h2 ash2(uint w) { return __builtin_bit_cast(h2, w); }

template <int CTRL>
__device__ __forceinline__ float dpp_add(float x) {
    int p = __builtin_amdgcn_update_dpp(0, __float_as_int(x), CTRL, 0xF, 0xF, false);
    return x + __int_as_float(p);
}
__device__ __forceinline__ float row_sum16(float x) {
    x = dpp_add<0xB1>(x);   // quad_perm xor1
    x = dpp_add<0x4E>(x);   // quad_perm xor2
    x = dpp_add<0x141>(x);  // row_half_mirror
    x = dpp_add<0x140>(x);  // row_mirror -> lane has its row-of-16 sum
    return x;
}

// Kernel 1: zero out, pack W2H/HOB into ws, and compute T[node][ty][128].
// Grid: N/8 blocks x 512 threads. Each wave computes one node x 4 types
// (16-lane group e4 = type), using the same packed f16 tables + fdot2
// accumulation order as the old stage 1 -> bit-identical t values.
__global__ __launch_bounds__(512) void bpnet_prep(
    const float* __restrict__ nodes,      // [N, 13]
    const float* __restrict__ bp_params,  // [4,13,128]
    const float* __restrict__ bp_bias,    // [4,1,128]
    const float* __restrict__ ho_params,  // [3,4,128,13]
    const float* __restrict__ ho_bias,    // [3,4,1,13]
    uint* __restrict__ ws,
    uint* __restrict__ outz, int out_n)
{
    __shared__ __align__(16) uint sh[L_N];
    const int tid  = threadIdx.x;
    const int gtid = blockIdx.x * 512 + tid;
    const int nthr = gridDim.x * 512;

    // ---- zero out (grid-stride uint4) ----
    const int n4 = out_n >> 2;
    for (int k = gtid; k < n4; k += nthr) ((uint4*)outz)[k] = uint4{0, 0, 0, 0};
    if (gtid < (out_n & 3)) outz[(n4 << 2) + gtid] = 0;

    // ---- pack global stage-2 tables (grid-stride over 10176 dwords) ----
    for (int k = gtid; k < TAB_N; k += nthr) {
        if (k < HOB_OFF) {                 // W2H [it][dd][c]
            const int c = k & 63, q = k >> 6;
            const int dd = q % 13, it = q / 13;
            ws[k] = pk(ho_params[(size_t)(it * RK + 2 * c) * DD + dd],
                       ho_params[(size_t)(it * RK + 2 * c + 1) * DD + dd]);
        } else {                           // HOB [it][16]
            const int j = k - HOB_OFF;
            const int dd = j & 15, it = j >> 4;
            ((float*)ws)[k] = (dd < DD) ? ho_bias[it * DD + dd] : 0.f;
        }
    }

    // ---- pack W1/B1 tables into this block's LDS ----
    for (int k = tid; k < L_N; k += 512) {
        if (k < L_W1B) {                   // W1A [ty][p][c], rank 8g+k
            const int c = k & 63, q = k >> 6;
            const int p = q % 7, ty = q / 7;
            const int r = 8 * (c >> 2) + (c & 3);
            const float a = bp_params[(ty * DD + 2 * p) * RK + r];
            const float b = (2 * p + 1 < DD) ? bp_params[(ty * DD + 2 * p + 1) * RK + r] : 0.f;
            sh[k] = pk(a, b);
        } else if (k < L_B1A) {            // W1B [ty][p][c], rank 8g+4+k
            const int j = k - L_W1B;
            const int c = j & 63, q = j >> 6;
            const int p = q % 7, ty = q / 7;
            const int r = 8 * (c >> 2) + 4 + (c & 3);
            const float a = bp_params[(ty * DD + 2 * p) * RK + r];
            const float b = (2 * p + 1 < DD) ? bp_params[(ty * DD + 2 * p + 1) * RK + r] : 0.f;
            sh[k] = pk(a, b);
        } else if (k < L_B1B) {            // B1A f32
            const int j = k - L_B1A;
            const int c = j & 63, ty = j >> 6;
            ((float*)sh)[k] = bp_bias[ty * RK + 8 * (c >> 2) + (c & 3)];
        } else {                           // B1B f32
            const int j = k - L_B1B;
            const int c = j & 63, ty = j >> 6;
            ((float*)sh)[k] = bp_bias[ty * RK + 8 * (c >> 2) + 4 + (c & 3)];
        }
    }
    __syncthreads();

    // ---- compute T: wave -> node, 16-lane group -> type ----
    const int lane = tid & 63;
    const int wv   = tid >> 6;
    const int ty   = lane >> 4;
    const int g    = lane & 15;
    const int nid  = blockIdx.x * 8 + wv;

    const float* nr_ = nodes + (size_t)nid * DD;   // wave-uniform row
    uint n[7];
#pragma unroll
    for (int p = 0; p < 6; ++p) n[p] = pk(nr_[2 * p], nr_[2 * p + 1]);
    n[6] = pk(nr_[12], 0.f);

    const float4 b0 = *(const float4*)((const float*)sh + L_B1A + ty * 64 + 4 * g);
    const float4 b1 = *(const float4*)((const float*)sh + L_B1B + ty * 64 + 4 * g);
    float s[8] = {b0.x, b0.y, b0.z, b0.w, b1.x, b1.y, b1.z, b1.w};
    const uint* wa = sh + L_W1A + ty * 7 * 64 + 4 * g;
    const uint* wb = sh + L_W1B + ty * 7 * 64 + 4 * g;
#pragma unroll
    for (int p = 0; p < 7; ++p) {
        const uint4 wA = *(const uint4*)(wa + p * 64);
        const uint4 wB = *(const uint4*)(wb + p * 64);
        const h2 nn = ash2(n[p]);
        s[0] = __builtin_amdgcn_fdot2(nn, ash2(wA.x), s[0], false);
        s[1] = __builtin_amdgcn_fdot2(nn, ash2(wA.y), s[1], false);
        s[2] = __builtin_amdgcn_fdot2(nn, ash2(wA.z), s[2], false);
        s[3] = __builtin_amdgcn_fdot2(nn, ash2(wA.w), s[3], false);
        s[4] = __builtin_amdgcn_fdot2(nn, ash2(wB.x), s[4], false);
        s[5] = __builtin_amdgcn_fdot2(nn, ash2(wB.y), s[5], false);
        s[6] = __builtin_amdgcn_fdot2(nn, ash2(wB.z), s[6], false);
        s[7] = __builtin_amdgcn_fdot2(nn, ash2(wB.w), s[7], false);
    }
    float* tp = (float*)ws + T_OFF + ((size_t)nid * NP + ty) * RK + 8 * g;
    *(float4*)tp       = float4{fmaxf(s[0], 0.f), fmaxf(s[1], 0.f), fmaxf(s[2], 0.f), fmaxf(s[3], 0.f)};
    *(float4*)(tp + 4) = float4{fmaxf(s[4], 0.f), fmaxf(s[5], 0.f), fmaxf(s[6], 0.f), fmaxf(s[7], 0.f)};
}

// Kernel 2: stage 2 only. 512 threads x 8 waves x 4 edges, 2 blocks/CU.
__global__ __launch_bounds__(512, 4) void bpnet_edge(
    const float* __restrict__ T,          // [N][4][128] f32 (relu'd t rows)
    const int*   __restrict__ edges,      // [E, 3]
    const int*   __restrict__ edge_types, // [E, 3]
    const uint*  __restrict__ tab,        // packed W2H/HOB (TAB_N dwords)
    float*       __restrict__ out)        // [N, 13] (pre-zeroed)
{
    __shared__ __align__(16) uint sh[TAB_N];
    const int tid  = threadIdx.x;
    const int lane = tid & 63;
    const int wv   = tid >> 6;        // 0..7
    const int e4   = lane >> 4;       // edge within wave's 4
    const int g    = lane & 15;       // rank octet 8g..8g+7
    const int eb   = (blockIdx.x * 8 + wv) * 4;

    // ---- wave metadata ----
    int ev = 0, tv = 0;
    if (lane < 12) {
        ev = edges[eb * OD + lane];
        tv = edge_types[eb * OD + lane];
    }
    int tg[OD], et[OD];
#pragma unroll
    for (int i = 0; i < OD; ++i) {
        tg[i] = __shfl(ev, e4 * OD + i, 64);
        et[i] = __shfl(tv, e4 * OD + i, 64);
    }

    // ---- issue coalesced t-row gathers early (hidden under staging) ----
    float4 ta[OD], tb[OD];
#pragma unroll
    for (int o = 0; o < OD; ++o) {
        const float* tp = T + ((size_t)tg[o] * NP + et[o]) * RK + 8 * g;
        ta[o] = *(const float4*)tp;
        tb[o] = *(const float4*)(tp + 4);
    }

    // ---- stage packed stage-2 tables into LDS (flat uint4 copy) ----
    for (int k4 = tid; k4 < TAB_N / 4; k4 += 512)
        ((uint4*)sh)[k4] = ((const uint4*)tab)[k4];
    __syncthreads();

    float t[OD][8];
#pragma unroll
    for (int o = 0; o < OD; ++o) {
        t[o][0] = ta[o].x; t[o][1] = ta[o].y; t[o][2] = ta[o].z; t[o][3] = ta[o].w;
        t[o][4] = tb[o].x; t[o][5] = tb[o].y; t[o][6] = tb[o].z; t[o][7] = tb[o].w;
    }

    // ---- stage 2: facts in registers -> h2, dot2 vs W2H rows ----
#pragma unroll
    for (int i = 0; i < OD; ++i) {
        const int j = (i + 1) % OD, k = (i + 2) % OD;
        uint fh[4];
#pragma unroll
        for (int r = 0; r < 4; ++r)
            fh[r] = pk(t[j][2 * r] * t[k][2 * r], t[j][2 * r + 1] * t[k][2 * r + 1]);
        const int it = i * NP + et[i];
        const uint* wb2 = sh + W2H_OFF + (it * DD) * 64 + 4 * g;
        float c[DD];
#pragma unroll
        for (int dd = 0; dd < DD; ++dd) {
            const uint4 w = *(const uint4*)(wb2 + dd * 64);
            float a = __builtin_amdgcn_fdot2(ash2(fh[0]), ash2(w.x), 0.f, false);
            a = __builtin_amdgcn_fdot2(ash2(fh[1]), ash2(w.y), a, false);
            a = __builtin_amdgcn_fdot2(ash2(fh[2]), ash2(w.z), a, false);
            a = __builtin_amdgcn_fdot2(ash2(fh[3]), ash2(w.w), a, false);
            c[dd] = a;
        }
#pragma unroll
        for (int dd = 0; dd < DD; ++dd) c[dd] = row_sum16(c[dd]);
        float q = c[0];
#pragma unroll
        for (int dd = 1; dd < DD; ++dd) q = (g == dd) ? c[dd] : q;
        q += ((const float*)(sh + HOB_OFF))[it * 16 + g];
        if (g < DD) atomicAdd(out + (size_t)tg[i] * DD + g, q);
    }
}

extern "C" void kernel_launch(void* const* d_in, const int* in_sizes, int n_in,
                              void* d_out, int out_size, void* d_ws, size_t ws_size,
                              hipStream_t stream) {
    const float* nodes      = (const float*)d_in[0];
    const float* bp_params  = (const float*)d_in[1];
    const float* bp_bias    = (const float*)d_in[2];
    const float* ho_params  = (const float*)d_in[3];
    const float* ho_bias    = (const float*)d_in[4];
    const int*   edges      = (const int*)d_in[5];
    const int*   edge_types = (const int*)d_in[6];
    float* out = (float*)d_out;
    uint*  ws  = (uint*)d_ws;

    const int N = in_sizes[0] / DD;   // 4096
    const int E = in_sizes[5] / OD;   // 16384

    // prep: zero out (poisoned before every timed call), pack stage-2
    // tables, compute T[node][ty][128] with bit-identical stage-1 math.
    bpnet_prep<<<N / 8, 512, 0, stream>>>(
        nodes, bp_params, bp_bias, ho_params, ho_bias, ws, (uint*)out, out_size);

    // edge kernel: E/32 = 512 blocks x 8 waves x 4 edges = 16384
    bpnet_edge<<<E / 32, 512, 0, stream>>>(
        (const float*)ws + T_OFF, edges, edge_types, ws, out);
}